// Round 5
// baseline (117.655 us; speedup 1.0000x reference)
//
#include <hip/hip_runtime.h>

// CRPS loss: preds [B=8, N=16, C=4, H=128, W=256] f32, gt [8,4,128,256] f32 -> scalar f32
// out = mean_over_points( sum_n |p_n - g|/N  -  sum_{i<j} |p_i - p_j| / (N*(N-1)) )
//
// Single-kernel, decoupled-lookback-style fusion:
//   - every block computes its tile partial, release-stores value + per-block flag
//     (flags 64B apart -> no same-cacheline contention; R2 showed same-ADDRESS
//     atomics cost ~5-7us for 1024 blocks, so that path is banned)
//   - block 0 then acquire-polls all 1024 flags and writes the final mean.
// Deadlock-free under any dispatch order: workers never wait.
// Safe under harness 0xAA ws re-poison: flags tested against MAGIC != 0xAAAAAAAA
// and rewritten on every call.

#define CHW      131072            // C*H*W = 4*128*256
#define CHW4     32768             // CHW/4 (float4 units)
#define NENS     16
#define BATCH    8
#define NPOINTS  (BATCH * CHW)     // 1,048,576 spatial points
#define NP4      (NPOINTS / 4)     // 262,144 float4 points
#define BLOCK    256
#define GRID1    (NP4 / BLOCK)     // 1024 blocks

#define MAGIC        0x5EED5EEDu
#define FLAG_STRIDE  16            // uints between flags (64 B -> one cacheline each)
#define FLAG_OFF_U32 16384         // flags start at byte 65536 in ws (partials live at [0,4KiB))

__global__ __launch_bounds__(BLOCK, 4) void crps_fused_kernel(
    const float4* __restrict__ preds,   // [B, N, CHW/4] in float4 units
    const float4* __restrict__ gt,      // [B, CHW/4]
    float* __restrict__ ws_f,           // workspace as float*
    float* __restrict__ out)            // scalar output
{
    unsigned int* ws_u = (unsigned int*)ws_f;

    // ---- worker phase: every block (including 0) computes one tile partial ----
    const int t  = blockIdx.x * BLOCK + threadIdx.x;  // float4 point id over [B, CHW/4]
    const int b  = t >> 15;                            // / CHW4
    const int s4 = t & (CHW4 - 1);

    const float4* pbase = preds + ((b * NENS) << 15) + s4;
    const float4 g = gt[t];

    float4 p[NENS];
#pragma unroll
    for (int n = 0; n < NENS; ++n)
        p[n] = pbase[n << 15];   // stride CHW4 float4 between ensemble members

    // 4 independent accumulator chains per term (x/y/z/w) for ILP
    float a1x = 0.f, a1y = 0.f, a1z = 0.f, a1w = 0.f;
    float a2x = 0.f, a2y = 0.f, a2z = 0.f, a2w = 0.f;
#pragma unroll
    for (int i = 0; i < NENS; ++i) {
        a1x += fabsf(p[i].x - g.x);
        a1y += fabsf(p[i].y - g.y);
        a1z += fabsf(p[i].z - g.z);
        a1w += fabsf(p[i].w - g.w);
#pragma unroll
        for (int j = i + 1; j < NENS; ++j) {
            a2x += fabsf(p[i].x - p[j].x);
            a2y += fabsf(p[i].y - p[j].y);
            a2z += fabsf(p[i].z - p[j].z);
            a2w += fabsf(p[i].w - p[j].w);
        }
    }
    float local = (a1x + a1y + a1z + a1w) * (1.0f / 16.0f)
                - (a2x + a2y + a2z + a2w) * (1.0f / 240.0f);

    // wave (64-lane) shuffle reduction
#pragma unroll
    for (int off = 32; off > 0; off >>= 1)
        local += __shfl_down(local, off, 64);

    __shared__ float smem[BLOCK / 64];
    const int lane = threadIdx.x & 63;
    const int wid  = threadIdx.x >> 6;
    if (lane == 0) smem[wid] = local;
    __syncthreads();

    if (threadIdx.x == 0) {
        float s = 0.0f;
#pragma unroll
        for (int w = 0; w < BLOCK / 64; ++w) s += smem[w];
        // publish: value (relaxed) then flag (release) — release orders the value store
        __hip_atomic_store(&ws_f[blockIdx.x], s, __ATOMIC_RELAXED, __HIP_MEMORY_SCOPE_AGENT);
        __hip_atomic_store(&ws_u[FLAG_OFF_U32 + blockIdx.x * FLAG_STRIDE], MAGIC,
                           __ATOMIC_RELEASE, __HIP_MEMORY_SCOPE_AGENT);
    }

    // ---- finisher phase: block 0 waits for all partials, writes the mean ----
    if (blockIdx.x != 0) return;

    float fsum = 0.0f;
#pragma unroll
    for (int k = 0; k < GRID1 / BLOCK; ++k) {          // 4 flags per thread
        const int idx = k * BLOCK + threadIdx.x;
        unsigned int* fl = &ws_u[FLAG_OFF_U32 + idx * FLAG_STRIDE];
        while (__hip_atomic_load(fl, __ATOMIC_ACQUIRE, __HIP_MEMORY_SCOPE_AGENT) != MAGIC)
            __builtin_amdgcn_s_sleep(1);
        fsum += __hip_atomic_load(&ws_f[idx], __ATOMIC_RELAXED, __HIP_MEMORY_SCOPE_AGENT);
    }

#pragma unroll
    for (int off = 32; off > 0; off >>= 1)
        fsum += __shfl_down(fsum, off, 64);

    __shared__ float smem2[BLOCK / 64];
    if (lane == 0) smem2[wid] = fsum;
    __syncthreads();
    if (threadIdx.x == 0) {
        float s = 0.0f;
#pragma unroll
        for (int w = 0; w < BLOCK / 64; ++w) s += smem2[w];
        out[0] = s * (1.0f / (float)NPOINTS);
    }
}

extern "C" void kernel_launch(void* const* d_in, const int* in_sizes, int n_in,
                              void* d_out, int out_size, void* d_ws, size_t ws_size,
                              hipStream_t stream) {
    const float4* preds = (const float4*)d_in[0];
    const float4* gt    = (const float4*)d_in[1];
    float* ws_f         = (float*)d_ws;     // partials [0,4KiB) + flags at 64KiB
    float* out          = (float*)d_out;

    crps_fused_kernel<<<GRID1, BLOCK, 0, stream>>>(preds, gt, ws_f, out);
}

// Round 6
// 93.773 us; speedup vs baseline: 1.2547x; 1.2547x over previous
//
#include <hip/hip_runtime.h>

// CRPS loss: preds [B=8, N=16, C=4, H=128, W=256] f32, gt [8,4,128,256] f32 -> scalar f32
// out = mean_over_points( sum_n |p_n - g|/N  -  sum_{i<j} |p_i - p_j| / (N*(N-1)) )
//
// Two-kernel deterministic reduction. Measured dead ends (do not retry):
//  - R2: fused via 1024 same-address device atomicAdds  -> +8 us (serialized RMW)
//  - R5: fused via decoupled-lookback w/ agent-scope acq/rel -> +24 us
//        (agent-scope release/acquire emit buffer_wbl2/buffer_inv on gfx950's
//         non-coherent per-XCD L2s -> whole-L2 writeback/invalidate storms)
//  - R3: 4-chain ILP split neutral; R4: sort-network (-35% VALU) neutral
//        -> worker kernel is purely memory-bound, compute fully hidden.

#define CHW      131072            // C*H*W = 4*128*256
#define CHW4     32768             // CHW/4 (float4 units)
#define NENS     16
#define BATCH    8
#define NPOINTS  (BATCH * CHW)     // 1,048,576 spatial points
#define NP4      (NPOINTS / 4)     // 262,144 float4 points
#define BLOCK    256
#define GRID1    (NP4 / BLOCK)     // 1024 blocks

__global__ __launch_bounds__(BLOCK) void crps_partial_kernel(
    const float4* __restrict__ preds,   // [B, N, CHW/4] in float4 units
    const float4* __restrict__ gt,      // [B, CHW/4]
    float* __restrict__ partial)        // [GRID1]
{
    const int t  = blockIdx.x * BLOCK + threadIdx.x;  // float4 point id over [B, CHW/4]
    const int b  = t >> 15;                            // / CHW4
    const int s4 = t & (CHW4 - 1);

    const float4* pbase = preds + ((b * NENS) << 15) + s4;
    const float4 g = gt[t];

    float4 p[NENS];
#pragma unroll
    for (int n = 0; n < NENS; ++n)
        p[n] = pbase[n << 15];   // stride CHW4 float4 between ensemble members

    // 4 independent accumulator chains per term (x/y/z/w) for ILP
    float a1x = 0.f, a1y = 0.f, a1z = 0.f, a1w = 0.f;
    float a2x = 0.f, a2y = 0.f, a2z = 0.f, a2w = 0.f;
#pragma unroll
    for (int i = 0; i < NENS; ++i) {
        a1x += fabsf(p[i].x - g.x);
        a1y += fabsf(p[i].y - g.y);
        a1z += fabsf(p[i].z - g.z);
        a1w += fabsf(p[i].w - g.w);
#pragma unroll
        for (int j = i + 1; j < NENS; ++j) {
            a2x += fabsf(p[i].x - p[j].x);
            a2y += fabsf(p[i].y - p[j].y);
            a2z += fabsf(p[i].z - p[j].z);
            a2w += fabsf(p[i].w - p[j].w);
        }
    }
    float local = (a1x + a1y + a1z + a1w) * (1.0f / 16.0f)
                - (a2x + a2y + a2z + a2w) * (1.0f / 240.0f);

    // wave (64-lane) shuffle reduction
#pragma unroll
    for (int off = 32; off > 0; off >>= 1)
        local += __shfl_down(local, off, 64);

    __shared__ float smem[BLOCK / 64];
    const int lane = threadIdx.x & 63;
    const int wid  = threadIdx.x >> 6;
    if (lane == 0) smem[wid] = local;
    __syncthreads();
    if (threadIdx.x == 0) {
        float s = 0.0f;
#pragma unroll
        for (int w = 0; w < BLOCK / 64; ++w) s += smem[w];
        partial[blockIdx.x] = s;
    }
}

__global__ __launch_bounds__(BLOCK) void crps_final_kernel(
    const float* __restrict__ partial, float* __restrict__ out)
{
    float local = 0.0f;
    for (int i = threadIdx.x; i < GRID1; i += BLOCK)
        local += partial[i];
#pragma unroll
    for (int off = 32; off > 0; off >>= 1)
        local += __shfl_down(local, off, 64);

    __shared__ float smem[BLOCK / 64];
    const int lane = threadIdx.x & 63;
    const int wid  = threadIdx.x >> 6;
    if (lane == 0) smem[wid] = local;
    __syncthreads();
    if (threadIdx.x == 0) {
        float s = 0.0f;
#pragma unroll
        for (int w = 0; w < BLOCK / 64; ++w) s += smem[w];
        out[0] = s * (1.0f / (float)NPOINTS);
    }
}

extern "C" void kernel_launch(void* const* d_in, const int* in_sizes, int n_in,
                              void* d_out, int out_size, void* d_ws, size_t ws_size,
                              hipStream_t stream) {
    const float4* preds = (const float4*)d_in[0];
    const float4* gt    = (const float4*)d_in[1];
    float* partial      = (float*)d_ws;     // GRID1 floats = 4 KiB scratch
    float* out          = (float*)d_out;

    crps_partial_kernel<<<GRID1, BLOCK, 0, stream>>>(preds, gt, partial);
    crps_final_kernel<<<1, BLOCK, 0, stream>>>(partial, out);
}